// Round 10
// baseline (223.399 us; speedup 1.0000x reference)
//
#include <hip/hip_runtime.h>
#include <cmath>

typedef __bf16 bf16x8 __attribute__((ext_vector_type(8)));
typedef __bf16 bf16x4 __attribute__((ext_vector_type(4)));
typedef float  f32x4  __attribute__((ext_vector_type(4)));
typedef unsigned uint2_ev __attribute__((ext_vector_type(2)));

static __device__ __forceinline__ f32x4 mfma16(bf16x8 a, bf16x8 b, f32x4 c) {
    return __builtin_amdgcn_mfma_f32_16x16x32_bf16(a, b, c, 0, 0, 0);
}

static __device__ __forceinline__ float fast_exp2(float x) {
#if __has_builtin(__builtin_amdgcn_exp2f)
    return __builtin_amdgcn_exp2f(x);
#else
    return exp2f(x);
#endif
}

// quad redistribution for P fragments: (a,b) = (X.dw, Y.dw) -> (W_lo, W_hi)
static __device__ __forceinline__ void quad_swap(unsigned &a, unsigned &b) {
#if __has_builtin(__builtin_amdgcn_permlane32_swap) && __has_builtin(__builtin_amdgcn_permlane16_swap)
    uint2_ev r32 = __builtin_amdgcn_permlane32_swap(a, b, false, false);
    uint2_ev r16 = __builtin_amdgcn_permlane16_swap(r32[0], r32[1], false, false);
    a = r16[0]; b = r16[1];
#else
    asm volatile("v_permlane32_swap_b32 %0, %1\n\t"
                 "v_permlane16_swap_b32 %0, %1"
                 : "+v"(a), "+v"(b));
#endif
}

static __device__ __forceinline__ void gload_lds16(const void* g, void* l) {
    __builtin_amdgcn_global_load_lds((const __attribute__((address_space(1))) void*)g,
                                     (__attribute__((address_space(3))) void*)l, 16, 0, 0);
}

// ---------------- workspace layout (bytes) ----------------
// GN folded into weights: xT holds RAW x transposed bf16; wS holds per-batch
// scaled [wq_s; wk_s; wv_s] (1536x512 bf16 per batch); beff per-batch eff biases.
#define OFF_STATS 0                           // 512 B
#define OFF_BEFF  1024                        // 2*1536*4 = 12 KB
#define OFF_W     16384                       // wS 3 MB + wo_bf 512 KB
#define OFF_XNT   (4u*1024*1024)              // 8 MB bf16 xT[b][p][c]; reused as attnT
#define OFF_QKT   (OFF_XNT + 8u*1024*1024)    // 16 MB bf16 qkT[b][p][1024] (q|k)
#define OFF_V     (OFF_QKT + 16u*1024*1024)   // 8 MB bf16 v[b][c][p]
#define OFF_OP    (OFF_V + 8u*1024*1024)      // NCH*8 MB bf16 Opart[ch][b][p][c]
#define CHUNK_O   4194304u                    // bf16 elems per chunk (2*4096*512)
#define CHUNK_L   65536u                      // fp32 elems per chunk (2*8*4096)

// ---------------- fused GroupNorm stats + transpose/cvt of RAW x ----------------
// Vectorized: float4 reads, bf16x8 writes. stats[g] = (sum, sumsq); xT[b][p][c].
__global__ __launch_bounds__(256) void gn_fuse(const float* __restrict__ x,
                                               float* __restrict__ stats,
                                               __bf16* __restrict__ xT) {
    int p0 = blockIdx.x * 64, c0 = blockIdx.y * 64, b = blockIdx.z;
    int tid = threadIdx.x, lane = tid & 63, wave = tid >> 6;
    __shared__ float t[64][68];     // [c][p], stride 68 floats (16B-aligned rows)
    __shared__ float red[4][8];
    float acc_s[4] = {0.f,0.f,0.f,0.f}, acc_ss[4] = {0.f,0.f,0.f,0.f};
    const int rr = tid >> 4;        // 0..15
    const int p4 = (tid & 15) * 4;  // float4 column
    #pragma unroll
    for (int i = 0; i < 4; ++i) {
        int cc = rr + 16*i;         // group-local index i == (cc>>4)
        float4 v = *(const float4*)&x[((size_t)(b*512 + c0 + cc) << 12) + p0 + p4];
        *(float4*)&t[cc][p4] = v;
        acc_s[i]  += v.x + v.y + v.z + v.w;
        acc_ss[i] += v.x*v.x + v.y*v.y + v.z*v.z + v.w*v.w;
    }
    #pragma unroll
    for (int g = 0; g < 4; ++g) {
        #pragma unroll
        for (int off = 1; off < 64; off <<= 1) {
            acc_s[g]  += __shfl_xor(acc_s[g],  off);
            acc_ss[g] += __shfl_xor(acc_ss[g], off);
        }
    }
    if (lane == 0) {
        #pragma unroll
        for (int g = 0; g < 4; ++g) { red[wave][g*2] = acc_s[g]; red[wave][g*2+1] = acc_ss[g]; }
    }
    __syncthreads();
    if (tid < 8) {
        float v0 = red[0][tid] + red[1][tid] + red[2][tid] + red[3][tid];
        int g = (b << 5) + (c0 >> 4) + (tid >> 1);
        atomicAdd(&stats[g*2 + (tid & 1)], v0);
    }
    // vectorized transpose-out: thread -> (pp, 8-channel chunk), 2 passes
    const int ch = tid & 7;
    #pragma unroll
    for (int w = 0; w < 2; ++w) {
        int pp = (tid >> 3) + 32*w;
        __bf16 ob[8];
        #pragma unroll
        for (int e = 0; e < 8; ++e) ob[e] = (__bf16)t[ch*8 + e][pp];
        *(bf16x8*)&xT[((size_t)(b*4096 + p0 + pp) << 9) + c0 + ch*8] = *(bf16x8*)ob;
    }
}

// ---------------- weight prep: scale by GN-affine, effective biases ----------------
// wS[b][row][c] = bf16(W[row][c] * s_b[c]) for rows [wq(0-511); wk(512-1023); wv(1024-1535)]
// beff[b][row]  = bias[row] + sum_c W[row][c] * t_b[c]
// bx in [48,64): plain cvt of wo (batch 0 only).
__global__ __launch_bounds__(256) void prep_w(const float* __restrict__ wq,
                                              const float* __restrict__ wkv,
                                              const float* __restrict__ wo,
                                              const float* __restrict__ bq,
                                              const float* __restrict__ bkv,
                                              const float* __restrict__ stats,
                                              const float* __restrict__ gw,
                                              const float* __restrict__ gb,
                                              __bf16* __restrict__ wS,
                                              __bf16* __restrict__ wo_bf,
                                              float* __restrict__ beff) {
    const int b = blockIdx.y, bx = blockIdx.x;
    const int tid = threadIdx.x, lane = tid & 63, wave = tid >> 6;
    if (bx >= 48) {
        if (b) return;
        int r0 = (bx - 48) * 32;
        #pragma unroll
        for (int ps = 0; ps < 8; ++ps) {
            int row = r0 + ps*4 + wave;
            __bf16 obuf[8];
            #pragma unroll
            for (int e = 0; e < 8; ++e) obuf[e] = (__bf16)wo[(size_t)row*512 + lane*8 + e];
            *(bf16x8*)&wo_bf[(size_t)row*512 + lane*8] = *(bf16x8*)obuf;
        }
        return;
    }
    __shared__ float sS[512], sT[512];
    for (int c = tid; c < 512; c += 256) {
        int g = (b << 5) + (c >> 4);
        float mu   = stats[g*2] * (1.f/65536.f);
        float var  = stats[g*2+1] * (1.f/65536.f) - mu*mu;
        float rstd = rsqrtf(var + 1e-5f);
        float s = rstd * gw[c];
        sS[c] = s;
        sT[c] = gb[c] - mu * s;
    }
    __syncthreads();
    int r0 = bx * 32;
    #pragma unroll
    for (int ps = 0; ps < 8; ++ps) {
        int row = r0 + ps*4 + wave;          // 0..1535
        const float* Wrow = (row < 512) ? (wq + (size_t)row*512) : (wkv + (size_t)(row-512)*512);
        float bias0 = (row < 512) ? bq[row] : bkv[row - 512];
        float bp = 0.f;
        __bf16 obuf[8];
        #pragma unroll
        for (int e = 0; e < 8; ++e) {
            int c = lane*8 + e;
            float wv_ = Wrow[c];
            obuf[e] = (__bf16)(wv_ * sS[c]);
            bp += wv_ * sT[c];
        }
        *(bf16x8*)&wS[((size_t)b*1536 + row)*512 + lane*8] = *(bf16x8*)obuf;
        #pragma unroll
        for (int off = 1; off < 64; off <<= 1) bp += __shfl_xor(bp, off);
        if (lane == 0) beff[b*1536 + row] = bias0 + bp;
    }
}

// ---------------- 128x128 MFMA GEMM v2: gload_lds DMA staging, BK=64, dbuf ----
// Staging pattern cloned from the verified attn kernel: linear LDS dest,
// inverse-swizzled global source, XOR-swizzled ds_read, ONE barrier per K-step.
__global__ __launch_bounds__(256) void gemm128_kernel(
    const __bf16* __restrict__ A, const __bf16* __restrict__ B,
    const float* __restrict__ bias, int nsplit,
    float scale0, void* __restrict__ out,
    int N, int K, long long strideA, long long strideB, long long strideO, int biasStride) {
    const int bz = blockIdx.z;
    A += strideA * bz;
    B += strideB * bz;
    const float* bb = bias + (size_t)bz * biasStride;
    const int m0 = blockIdx.x * 128, n0 = blockIdx.y * 128;
    const int tid = threadIdx.x, lane = tid & 63, wave = tid >> 6;
    const int quad = lane >> 4, l16 = lane & 15;
    const int wm = (wave >> 1) * 64, wn = (wave & 1) * 64;

    __shared__ __attribute__((aligned(16))) __bf16 lds_a[2][128][64];
    __shared__ __attribute__((aligned(16))) __bf16 lds_b[2][128][64];

    f32x4 acc[4][4];
    #pragma unroll
    for (int mt = 0; mt < 4; ++mt)
        #pragma unroll
        for (int nt = 0; nt < 4; ++nt)
            #pragma unroll
            for (int r = 0; r < 4; ++r) acc[mt][nt][r] = 0.f;

    const int myrow = (wave << 3) + (lane >> 3);        // 0..31
    const int mych  = ((lane & 7) ^ (myrow & 7)) << 3;  // inverse-swizzled elem chunk
    const __bf16* Ab = A + (size_t)(m0 + myrow) * K + mych;
    const __bf16* Bb = B + (size_t)(n0 + myrow) * K + mych;

    auto stage = [&](int buf, int kt) {
        char* la = (char*)(&lds_a[buf][0][0]) + (wave << 10);
        char* lb = (char*)(&lds_b[buf][0][0]) + (wave << 10);
        #pragma unroll
        for (int i = 0; i < 4; ++i) {
            gload_lds16(Ab + kt + (size_t)(32*i) * K, la + i*4096);
            gload_lds16(Bb + kt + (size_t)(32*i) * K, lb + i*4096);
        }
    };

    stage(0, 0);
    const int NK = K >> 6;
    for (int k8 = 0; k8 < NK; ++k8) {
        __syncthreads();
        const int cur = k8 & 1;
        if (k8 + 1 < NK) stage(cur ^ 1, (k8 + 1) << 6);
        #pragma unroll
        for (int kh = 0; kh < 2; ++kh) {
            bf16x8 af[4], bfr[4];
            #pragma unroll
            for (int mt = 0; mt < 4; ++mt)
                af[mt] = *(const bf16x8*)&lds_a[cur][wm + mt*16 + l16][(((kh<<2)|quad) ^ (l16 & 7)) * 8];
            #pragma unroll
            for (int nt = 0; nt < 4; ++nt)
                bfr[nt] = *(const bf16x8*)&lds_b[cur][wn + nt*16 + l16][(((kh<<2)|quad) ^ (l16 & 7)) * 8];
            #pragma unroll
            for (int mt = 0; mt < 4; ++mt)
                #pragma unroll
                for (int nt = 0; nt < 4; ++nt)
                    acc[mt][nt] = mfma16(af[mt], bfr[nt], acc[mt][nt]);
        }
    }

    #pragma unroll
    for (int mt = 0; mt < 4; ++mt) {
        const int mrow = m0 + wm + mt*16 + quad*4;
        #pragma unroll
        for (int nt = 0; nt < 4; ++nt) {
            const int ncol = n0 + wn + nt*16 + l16;
            #pragma unroll
            for (int r = 0; r < 4; ++r) {
                const int m = mrow + r;
                float val = acc[mt][nt][r] + bb[ncol];
                if (ncol < nsplit) val *= scale0;
                ((__bf16*)out)[(size_t)strideO * bz + (size_t)m * N + ncol] = (__bf16)val;
            }
        }
    }
}

// ---------------- 64x128 MFMA GEMM v3 (M-tile 64) ----------------------------
// COMB=0: B staged via DMA (as round 8/9).
// COMB=NCH>0: B is Opart; the split-K combine (sum chunks, normalize by Lp)
// is fused into reg-staged B with write-late (loads issued after barrier,
// combine+ds_write after the MFMA block). BK=64 tile spans exactly one head
// (h = kt>>6), so one denominator per staged row. Numerics identical to the
// old attn_combine (f32 sum -> *1/l -> bf16).
template<int OUT_F32, int HAS_RES, int COMB>
__global__ __launch_bounds__(256) void gemm64_kernel(
    const __bf16* __restrict__ A, const __bf16* __restrict__ B,
    const float* __restrict__ bias, const float* __restrict__ res,
    const float* __restrict__ Lp,
    void* __restrict__ out,
    int N, int K, long long strideA, long long strideB, long long strideO, int biasStride) {
    const int bz = blockIdx.z;
    A += strideA * bz;
    B += strideB * bz;
    const float* bb = bias + (size_t)bz * biasStride;
    const int m0 = blockIdx.x * 64, n0 = blockIdx.y * 128;
    const int tid = threadIdx.x, lane = tid & 63, wave = tid >> 6;
    const int quad = lane >> 4, l16 = lane & 15;
    const int wn = wave * 32;

    __shared__ __attribute__((aligned(16))) __bf16 lds_a[2][64][64];
    __shared__ __attribute__((aligned(16))) __bf16 lds_b[2][128][64];

    f32x4 acc[4][2];
    #pragma unroll
    for (int mt = 0; mt < 4; ++mt)
        #pragma unroll
        for (int nt = 0; nt < 2; ++nt)
            #pragma unroll
            for (int r = 0; r < 4; ++r) acc[mt][nt][r] = 0.f;

    const int myrow = (wave << 3) + (lane >> 3);        // 0..31
    const int mych  = ((lane & 7) ^ (myrow & 7)) << 3;
    const __bf16* Ab = A + (size_t)(m0 + myrow) * K + mych;
    const __bf16* Bb = B + (size_t)(n0 + myrow) * K + mych;   // COMB: unused

    auto stageA = [&](int buf, int kt) {
        char* la = (char*)(&lds_a[buf][0][0]) + (wave << 10);
        #pragma unroll
        for (int i = 0; i < 2; ++i)
            gload_lds16(Ab + kt + (size_t)(32*i) * K, la + i*4096);
    };
    auto stageB_dma = [&](int buf, int kt) {
        char* lb = (char*)(&lds_b[buf][0][0]) + (wave << 10);
        #pragma unroll
        for (int i = 0; i < 4; ++i)
            gload_lds16(Bb + kt + (size_t)(32*i) * K, lb + i*4096);
    };

    // COMB state: raw chunk fragments + denominators (write-late)
    bf16x8 brq[4][COMB ? COMB : 1];
    float  lq [4][COMB ? COMB : 1];
    auto loadB = [&](int kt) {
        if constexpr (COMB) {
            const int h = kt >> 6;
            #pragma unroll
            for (int i = 0; i < 4; ++i) {
                const int p = n0 + myrow + 32*i;
                const size_t bi = (((size_t)bz*4096 + p) << 9) + kt + mych;
                const size_t li = ((size_t)((bz*8 + h)) << 12) + p;
                #pragma unroll
                for (int ch = 0; ch < COMB; ++ch) {
                    brq[i][ch] = *(const bf16x8*)&B[(size_t)ch * CHUNK_O + bi];
                    lq[i][ch]  = Lp[(size_t)ch * CHUNK_L + li];
                }
            }
        }
    };
    auto writeB = [&](int buf) {
        if constexpr (COMB) {
            #pragma unroll
            for (int i = 0; i < 4; ++i) {
                float l = 0.f;
                #pragma unroll
                for (int ch = 0; ch < COMB; ++ch) l += lq[i][ch];
                float inv = 1.f / l;
                __bf16 ob[8];
                #pragma unroll
                for (int e = 0; e < 8; ++e) {
                    float a = 0.f;
                    #pragma unroll
                    for (int ch = 0; ch < COMB; ++ch) a += (float)brq[i][ch][e];
                    ob[e] = (__bf16)(a * inv);
                }
                *(bf16x8*)&lds_b[buf][myrow + 32*i][(lane & 7) * 8] = *(bf16x8*)ob;
            }
        }
    };

    stageA(0, 0);
    if constexpr (COMB) { loadB(0); writeB(0); }
    else stageB_dma(0, 0);

    const int NK = K >> 6;
    for (int k8 = 0; k8 < NK; ++k8) {
        __syncthreads();
        const int cur = k8 & 1;
        if (k8 + 1 < NK) {
            stageA(cur ^ 1, (k8 + 1) << 6);
            if constexpr (COMB) loadB((k8 + 1) << 6);
            else stageB_dma(cur ^ 1, (k8 + 1) << 6);
        }
        #pragma unroll
        for (int kh = 0; kh < 2; ++kh) {
            bf16x8 af[4], bfr[2];
            #pragma unroll
            for (int mt = 0; mt < 4; ++mt)
                af[mt] = *(const bf16x8*)&lds_a[cur][mt*16 + l16][(((kh<<2)|quad) ^ (l16 & 7)) * 8];
            #pragma unroll
            for (int nt = 0; nt < 2; ++nt)
                bfr[nt] = *(const bf16x8*)&lds_b[cur][wn + nt*16 + l16][(((kh<<2)|quad) ^ (l16 & 7)) * 8];
            #pragma unroll
            for (int mt = 0; mt < 4; ++mt)
                #pragma unroll
                for (int nt = 0; nt < 2; ++nt)
                    acc[mt][nt] = mfma16(af[mt], bfr[nt], acc[mt][nt]);
        }
        if constexpr (COMB) { if (k8 + 1 < NK) writeB(cur ^ 1); }
    }

    #pragma unroll
    for (int mt = 0; mt < 4; ++mt) {
        const int mrow = m0 + mt*16 + quad*4;
        #pragma unroll
        for (int nt = 0; nt < 2; ++nt) {
            const int ncol = n0 + wn + nt*16 + l16;
            #pragma unroll
            for (int r = 0; r < 4; ++r) {
                const int m = mrow + r;
                float val = acc[mt][nt][r] + bb[m];
                const size_t idx = (size_t)strideO * bz + (size_t)m * N + ncol;
                if constexpr (HAS_RES) val += res[idx];
                if constexpr (OUT_F32) ((float*)out)[idx] = val;
                else ((__bf16*)out)[idx] = (__bf16)val;
            }
        }
    }
}

// ---------------- flash attention v9 (round-7 verified, 78.7 us) ----------------
// Ones-column MFMA row-sums (VALU-lsum variant spills: rounds 2 & 6).
// setprio(1) around compute (verified +1.5us round 7).
// NCH=3 -> grid 16x16x3 = 768 blocks = 3 resident blocks/CU (measured optimum;
// NCH=2's 512 blocks dropped occupancy to 18% and cost +6us -- round 8).
// Iter split 22/21/21 (kt0 = 0/1408/2752).
// qkT: [b][p][1024] bf16 (q pre-scaled by 0.125*log2e); v: [b][c][p] bf16
template<int NCH>
__global__ __launch_bounds__(256, 3) void attn_kernel(const __bf16* __restrict__ qkT,
                                                      const __bf16* __restrict__ v,
                                                      __bf16* __restrict__ attnT,
                                                      __bf16* __restrict__ Opart,
                                                      float* __restrict__ Lpart) {
    const int b = blockIdx.y >> 3, h = blockIdx.y & 7;
    const int chunk = (NCH > 1) ? blockIdx.z : 0;
    int NITER, kt0;
    if constexpr (NCH == 3) {
        NITER = (chunk == 0) ? 22 : 21;
        kt0   = (chunk == 0) ? 0 : (chunk == 1 ? 1408 : 2752);
    } else {
        NITER = 64 / NCH;
        kt0   = chunk * (4096 / NCH);
    }
    const int tid = threadIdx.x;
    const int wave = tid >> 6, lane = tid & 63;
    const int quad = lane >> 4, l16 = lane & 15;
    const int qbase = blockIdx.x * 256 + wave * 64;   // 64 queries per wave

    const __bf16* qkTb = qkT + ((size_t)b << 22);
    const __bf16* vb   = v   + ((size_t)b << 21);

    // double-buffered K/V tiles, XOR-swizzled on 16B chunks: 4x8 KB = 32 KB
    __shared__ __attribute__((aligned(16))) __bf16 lds_k[2][64][64];
    __shared__ __attribute__((aligned(16))) __bf16 lds_v[2][64][64];

    bf16x8 aq[4][2];
    #pragma unroll
    for (int mt = 0; mt < 4; ++mt) {
        const __bf16* qrow = qkTb + (size_t)(qbase + mt*16 + l16) * 1024 + h*64 + quad*8;
        aq[mt][0] = *(const bf16x8*)qrow;
        aq[mt][1] = *(const bf16x8*)(qrow + 32);
    }
    f32x4 o[4][5];   // o[mt][4] accumulates row-sums l via register-ones MFMA
    #pragma unroll
    for (int mt = 0; mt < 4; ++mt)
        #pragma unroll
        for (int dt = 0; dt < 5; ++dt)
            #pragma unroll
            for (int r = 0; r < 4; ++r) o[mt][dt][r] = 0.f;
    const f32x4 kZero = {0.f, 0.f, 0.f, 0.f};

    bf16x8 onesb;
    #pragma unroll
    for (int e = 0; e < 8; ++e) onesb[e] = (__bf16)1.0f;

    // DMA staging geometry: global_load_lds writes linear (wave base + lane*16B).
    // Inverse-swizzle the SOURCE so the linear write realizes col' = col ^ (row&7).
    const int myrow = (wave << 3) + (lane >> 3);
    const int mych  = ((lane & 7) ^ (myrow & 7)) << 3;     // element chunk offset
    const __bf16* kgb = qkTb + (size_t)myrow * 1024 + 512 + h*64 + mych;
    const __bf16* vgb = vb + ((size_t)(h*64 + myrow) << 12) + mych;

    auto stage = [&](int buf, int kt) {
        char* kb = (char*)(&lds_k[buf][0][0]) + (wave << 10);
        char* vp = (char*)(&lds_v[buf][0][0]) + (wave << 10);
        const __bf16* kg = kgb + (size_t)kt * 1024;
        const __bf16* vg = vgb + kt;
        gload_lds16(kg,                       kb);          // K rows 0..31
        gload_lds16(kg + 32*1024,             kb + 4096);   // K rows 32..63
        gload_lds16(vg,                       vp);          // V rows (d) 0..31
        gload_lds16(vg + ((size_t)32 << 12),  vp + 4096);   // V rows (d) 32..63
    };

    stage(0, kt0);   // prologue: tile 0 -> buf 0 (drained by first barrier)

    for (int it = 0; it < NITER; ++it) {
        __syncthreads();           // waits vmcnt(0): tile `it` staged; prior reads done
        const int cur = it & 1;
        if (it + 1 < NITER) stage(cur ^ 1, kt0 + (it + 1) * 64);

        #pragma unroll
        for (int kh = 0; kh < 2; ++kh) {        // key half: keys kh*32 .. kh*32+31
            __builtin_amdgcn_s_setprio(1);
            unsigned pd[4][4];                  // [mt][dword]: nt=2kh(d0,d1), nt=2kh+1(d0,d1)
            #pragma unroll
            for (int j = 0; j < 2; ++j) {
                const int nt = kh*2 + j;
                const int kr = nt*16 + l16;
                bf16x8 bk0 = *(const bf16x8*)&lds_k[cur][kr][( quad      ^ (l16 & 7)) * 8];
                bf16x8 bk1 = *(const bf16x8*)&lds_k[cur][kr][((4 + quad) ^ (l16 & 7)) * 8];
                #pragma unroll
                for (int mt = 0; mt < 4; ++mt) {
                    f32x4 s = mfma16(bk1, aq[mt][1], mfma16(bk0, aq[mt][0], kZero));
                    f32x4 p;
                    #pragma unroll
                    for (int r = 0; r < 4; ++r) p[r] = fast_exp2(s[r]);
                    bf16x4 pb = __builtin_convertvector(p, bf16x4);
                    union { bf16x4 v; unsigned d[2]; } u; u.v = pb;
                    pd[mt][j*2]     = u.d[0];
                    pd[mt][j*2 + 1] = u.d[1];
                }
            }
            // in-register quad redistribution: (X.dw,Y.dw) -> (W_lo, W_hi)
            bf16x8 pa[4];
            #pragma unroll
            for (int mt = 0; mt < 4; ++mt) {
                unsigned x0 = pd[mt][0], x1 = pd[mt][1];
                unsigned y0 = pd[mt][2], y1 = pd[mt][3];
                quad_swap(x0, y0);   // -> W0, W2
                quad_swap(x1, y1);   // -> W1, W3
                union { unsigned d[4]; bf16x8 v; } u;
                u.d[0] = x0; u.d[1] = x1; u.d[2] = y0; u.d[3] = y1;
                pa[mt] = u.v;
            }
            #pragma unroll
            for (int dt = 0; dt < 4; ++dt) {
                bf16x8 bv = *(const bf16x8*)&lds_v[cur][dt*16 + l16][((kh*4 + quad) ^ (l16 & 7)) * 8];
                #pragma unroll
                for (int mt = 0; mt < 4; ++mt)
                    o[mt][dt] = mfma16(pa[mt], bv, o[mt][dt]);
            }
            #pragma unroll
            for (int mt = 0; mt < 4; ++mt)
                o[mt][4] = mfma16(pa[mt], onesb, o[mt][4]);
            __builtin_amdgcn_s_setprio(0);
        }
    }

    if constexpr (NCH > 1) {
        __bf16* Ob = Opart + (size_t)chunk * CHUNK_O;
        #pragma unroll
        for (int mt = 0; mt < 4; ++mt)
            #pragma unroll
            for (int dt = 0; dt < 4; ++dt)
                #pragma unroll
                for (int r = 0; r < 4; ++r) {
                    size_t row = (size_t)b * 4096 + qbase + mt*16 + quad*4 + r;
                    Ob[(row << 9) + (h << 6) + dt*16 + l16] = (__bf16)o[mt][dt][r];
                }
        if (l16 == 0) {
            #pragma unroll
            for (int mt = 0; mt < 4; ++mt)
                #pragma unroll
                for (int r = 0; r < 4; ++r) {
                    int p = qbase + mt*16 + quad*4 + r;
                    Lpart[(size_t)chunk * CHUNK_L + (size_t)(((b*8 + h)) << 12) + p] = o[mt][4][r];
                }
        }
    } else {
        #pragma unroll
        for (int mt = 0; mt < 4; ++mt) {
            float inv[4];
            #pragma unroll
            for (int r = 0; r < 4; ++r)
                inv[r] = 1.f / __shfl(o[mt][4][r], lane & 48);   // broadcast col-0 lane of quad
            #pragma unroll
            for (int dt = 0; dt < 4; ++dt)
                #pragma unroll
                for (int r = 0; r < 4; ++r) {
                    size_t row = (size_t)b * 4096 + qbase + mt*16 + quad*4 + r;
                    attnT[(row << 9) + (h << 6) + dt*16 + l16] = (__bf16)(o[mt][dt][r] * inv[r]);
                }
        }
    }
}

extern "C" void kernel_launch(void* const* d_in, const int* in_sizes, int n_in,
                              void* d_out, int out_size, void* d_ws, size_t ws_size,
                              hipStream_t stream) {
    const float* x   = (const float*)d_in[0];
    const float* gnw = (const float*)d_in[1];
    const float* gnb = (const float*)d_in[2];
    const float* wq  = (const float*)d_in[3];
    const float* bq  = (const float*)d_in[4];
    const float* wkv = (const float*)d_in[5];
    const float* bkv = (const float*)d_in[6];
    const float* wo  = (const float*)d_in[7];
    const float* bo  = (const float*)d_in[8];
    float* out = (float*)d_out;

    char* ws = (char*)d_ws;
    float*  stats  = (float*)(ws + OFF_STATS);
    float*  beff   = (float*)(ws + OFF_BEFF);
    __bf16* wS     = (__bf16*)(ws + OFF_W);            // [b][1536][512]
    __bf16* wo_bf  = wS + 2u*1536*512;                 // 512x512
    __bf16* xT     = (__bf16*)(ws + OFF_XNT);          // raw x transposed bf16
    __bf16* qkT    = (__bf16*)(ws + OFF_QKT);
    __bf16* vv     = (__bf16*)(ws + OFF_V);
    __bf16* Opart  = (__bf16*)(ws + OFF_OP);
    __bf16* attnT  = xT;   // xT dead after v-projection; reuse (NCH==1 path only)

    // ws requirement for NCH chunks: OFF_OP + NCH*(8 MB Opart + 256 KB Lpart)
    const size_t need3 = (size_t)OFF_OP + 3u * (CHUNK_O * 2 + CHUNK_L * 4);
    const size_t need2 = (size_t)OFF_OP + 2u * (CHUNK_O * 2 + CHUNK_L * 4);
    const int nch = (ws_size >= need3) ? 3 : (ws_size >= need2 ? 2 : 1);
    float* Lpart = (float*)(ws + OFF_OP + (size_t)nch * CHUNK_O * 2);

    hipMemsetAsync(stats, 0, 512, stream);
    // fused GN stats + raw-x transpose/cvt
    gn_fuse<<<dim3(64, 8, 2), 256, 0, stream>>>(x, stats, xT);
    // per-batch scaled weights + effective biases (+ wo cvt)
    prep_w<<<dim3(64, 2), 256, 0, stream>>>(wq, wkv, wo, bq, bkv, stats, gnw, gnb,
                                            wS, wo_bf, beff);

    const long long S  = 2097152LL;   // 4096*512
    const long long S2 = 4194304LL;   // 4096*1024
    const long long SW = 1536LL*512;  // per-batch weight stride
    // qkT[p][c2] = xT * [wq_s;wk_s]^T ; q cols scaled by 0.125*log2(e) for exp2 softmax
    gemm128_kernel<<<dim3(32, 8, 2), 256, 0, stream>>>(
        xT, wS, beff, 512, 0.125f * 1.44269504f, qkT, 1024, 512, S, SW, S2, 1536);
    // v[c][p] = wv_s * xT^T  (M=512, N=4096)
    gemm64_kernel<0,0,0><<<dim3(8, 32, 2), 256, 0, stream>>>(
        wS + 1024*512, xT, beff + 1024, nullptr, nullptr, vv, 4096, 512, SW, S, S, 1536);

    if (nch == 3) {
        attn_kernel<3><<<dim3(16, 16, 3), 256, 0, stream>>>(qkT, vv, nullptr, Opart, Lpart);
        // out[c][p] = wo * attnOut + bo + residual; combine fused into B staging
        gemm64_kernel<1,1,3><<<dim3(8, 32, 2), 256, 0, stream>>>(
            wo_bf, Opart, bo, x, Lpart, out, 4096, 512, 0, 0, S, 0);
    } else if (nch == 2) {
        attn_kernel<2><<<dim3(16, 16, 2), 256, 0, stream>>>(qkT, vv, nullptr, Opart, Lpart);
        gemm64_kernel<1,1,2><<<dim3(8, 32, 2), 256, 0, stream>>>(
            wo_bf, Opart, bo, x, Lpart, out, 4096, 512, 0, 0, S, 0);
    } else {
        attn_kernel<1><<<dim3(16, 16, 1), 256, 0, stream>>>(qkT, vv, attnT, nullptr, nullptr);
        gemm64_kernel<1,1,0><<<dim3(8, 32, 2), 256, 0, stream>>>(
            wo_bf, attnT, bo, x, nullptr, out, 4096, 512, 0, S, S, 0);
    }
}

// Round 11
// 209.002 us; speedup vs baseline: 1.0689x; 1.0689x over previous
//
#include <hip/hip_runtime.h>
#include <cmath>

typedef __bf16 bf16x8 __attribute__((ext_vector_type(8)));
typedef __bf16 bf16x4 __attribute__((ext_vector_type(4)));
typedef float  f32x4  __attribute__((ext_vector_type(4)));
typedef unsigned uint2_ev __attribute__((ext_vector_type(2)));

static __device__ __forceinline__ f32x4 mfma16(bf16x8 a, bf16x8 b, f32x4 c) {
    return __builtin_amdgcn_mfma_f32_16x16x32_bf16(a, b, c, 0, 0, 0);
}

static __device__ __forceinline__ float fast_exp2(float x) {
#if __has_builtin(__builtin_amdgcn_exp2f)
    return __builtin_amdgcn_exp2f(x);
#else
    return exp2f(x);
#endif
}

// quad redistribution for P fragments: (a,b) = (X.dw, Y.dw) -> (W_lo, W_hi)
static __device__ __forceinline__ void quad_swap(unsigned &a, unsigned &b) {
#if __has_builtin(__builtin_amdgcn_permlane32_swap) && __has_builtin(__builtin_amdgcn_permlane16_swap)
    uint2_ev r32 = __builtin_amdgcn_permlane32_swap(a, b, false, false);
    uint2_ev r16 = __builtin_amdgcn_permlane16_swap(r32[0], r32[1], false, false);
    a = r16[0]; b = r16[1];
#else
    asm volatile("v_permlane32_swap_b32 %0, %1\n\t"
                 "v_permlane16_swap_b32 %0, %1"
                 : "+v"(a), "+v"(b));
#endif
}

static __device__ __forceinline__ void gload_lds16(const void* g, void* l) {
    __builtin_amdgcn_global_load_lds((const __attribute__((address_space(1))) void*)g,
                                     (__attribute__((address_space(3))) void*)l, 16, 0, 0);
}

// ---------------- workspace layout (bytes) ----------------
// GN folded into weights: xT holds RAW x transposed bf16; wS holds per-batch
// scaled [wq_s; wk_s; wv_s] (1536x512 bf16 per batch); beff per-batch eff biases.
#define OFF_STATS 0                           // 512 B
#define OFF_BEFF  1024                        // 2*1536*4 = 12 KB
#define OFF_W     16384                       // wS 3 MB + wo_bf 512 KB
#define OFF_XNT   (4u*1024*1024)              // 8 MB bf16 xT[b][p][c]; reused as attnT
#define OFF_QKT   (OFF_XNT + 8u*1024*1024)    // 16 MB bf16 qkT[b][p][1024] (q|k)
#define OFF_V     (OFF_QKT + 16u*1024*1024)   // 8 MB bf16 v[b][c][p]
#define OFF_OP    (OFF_V + 8u*1024*1024)      // NCH*8 MB bf16 Opart[ch][b][p][c]
#define CHUNK_O   4194304u                    // bf16 elems per chunk (2*4096*512)
#define CHUNK_L   65536u                      // fp32 elems per chunk (2*8*4096)

// ---------------- fused GroupNorm stats + transpose/cvt of RAW x ----------------
// Vectorized: float4 reads, bf16x8 writes. stats[g] = (sum, sumsq); xT[b][p][c].
__global__ __launch_bounds__(256) void gn_fuse(const float* __restrict__ x,
                                               float* __restrict__ stats,
                                               __bf16* __restrict__ xT) {
    int p0 = blockIdx.x * 64, c0 = blockIdx.y * 64, b = blockIdx.z;
    int tid = threadIdx.x, lane = tid & 63, wave = tid >> 6;
    __shared__ float t[64][68];     // [c][p], stride 68 floats (16B-aligned rows)
    __shared__ float red[4][8];
    float acc_s[4] = {0.f,0.f,0.f,0.f}, acc_ss[4] = {0.f,0.f,0.f,0.f};
    const int rr = tid >> 4;        // 0..15
    const int p4 = (tid & 15) * 4;  // float4 column
    #pragma unroll
    for (int i = 0; i < 4; ++i) {
        int cc = rr + 16*i;         // group-local index i == (cc>>4)
        float4 v = *(const float4*)&x[((size_t)(b*512 + c0 + cc) << 12) + p0 + p4];
        *(float4*)&t[cc][p4] = v;
        acc_s[i]  += v.x + v.y + v.z + v.w;
        acc_ss[i] += v.x*v.x + v.y*v.y + v.z*v.z + v.w*v.w;
    }
    #pragma unroll
    for (int g = 0; g < 4; ++g) {
        #pragma unroll
        for (int off = 1; off < 64; off <<= 1) {
            acc_s[g]  += __shfl_xor(acc_s[g],  off);
            acc_ss[g] += __shfl_xor(acc_ss[g], off);
        }
    }
    if (lane == 0) {
        #pragma unroll
        for (int g = 0; g < 4; ++g) { red[wave][g*2] = acc_s[g]; red[wave][g*2+1] = acc_ss[g]; }
    }
    __syncthreads();
    if (tid < 8) {
        float v0 = red[0][tid] + red[1][tid] + red[2][tid] + red[3][tid];
        int g = (b << 5) + (c0 >> 4) + (tid >> 1);
        atomicAdd(&stats[g*2 + (tid & 1)], v0);
    }
    // vectorized transpose-out: thread -> (pp, 8-channel chunk), 2 passes
    const int ch = tid & 7;
    #pragma unroll
    for (int w = 0; w < 2; ++w) {
        int pp = (tid >> 3) + 32*w;
        __bf16 ob[8];
        #pragma unroll
        for (int e = 0; e < 8; ++e) ob[e] = (__bf16)t[ch*8 + e][pp];
        *(bf16x8*)&xT[((size_t)(b*4096 + p0 + pp) << 9) + c0 + ch*8] = *(bf16x8*)ob;
    }
}

// ---------------- weight prep: scale by GN-affine, effective biases ----------------
// wS[b][row][c] = bf16(W[row][c] * s_b[c]) for rows [wq(0-511); wk(512-1023); wv(1024-1535)]
// beff[b][row]  = bias[row] + sum_c W[row][c] * t_b[c]
// bx in [48,64): plain cvt of wo (batch 0 only).
__global__ __launch_bounds__(256) void prep_w(const float* __restrict__ wq,
                                              const float* __restrict__ wkv,
                                              const float* __restrict__ wo,
                                              const float* __restrict__ bq,
                                              const float* __restrict__ bkv,
                                              const float* __restrict__ stats,
                                              const float* __restrict__ gw,
                                              const float* __restrict__ gb,
                                              __bf16* __restrict__ wS,
                                              __bf16* __restrict__ wo_bf,
                                              float* __restrict__ beff) {
    const int b = blockIdx.y, bx = blockIdx.x;
    const int tid = threadIdx.x, lane = tid & 63, wave = tid >> 6;
    if (bx >= 48) {
        if (b) return;
        int r0 = (bx - 48) * 32;
        #pragma unroll
        for (int ps = 0; ps < 8; ++ps) {
            int row = r0 + ps*4 + wave;
            __bf16 obuf[8];
            #pragma unroll
            for (int e = 0; e < 8; ++e) obuf[e] = (__bf16)wo[(size_t)row*512 + lane*8 + e];
            *(bf16x8*)&wo_bf[(size_t)row*512 + lane*8] = *(bf16x8*)obuf;
        }
        return;
    }
    __shared__ float sS[512], sT[512];
    for (int c = tid; c < 512; c += 256) {
        int g = (b << 5) + (c >> 4);
        float mu   = stats[g*2] * (1.f/65536.f);
        float var  = stats[g*2+1] * (1.f/65536.f) - mu*mu;
        float rstd = rsqrtf(var + 1e-5f);
        float s = rstd * gw[c];
        sS[c] = s;
        sT[c] = gb[c] - mu * s;
    }
    __syncthreads();
    int r0 = bx * 32;
    #pragma unroll
    for (int ps = 0; ps < 8; ++ps) {
        int row = r0 + ps*4 + wave;          // 0..1535
        const float* Wrow = (row < 512) ? (wq + (size_t)row*512) : (wkv + (size_t)(row-512)*512);
        float bias0 = (row < 512) ? bq[row] : bkv[row - 512];
        float bp = 0.f;
        __bf16 obuf[8];
        #pragma unroll
        for (int e = 0; e < 8; ++e) {
            int c = lane*8 + e;
            float wv_ = Wrow[c];
            obuf[e] = (__bf16)(wv_ * sS[c]);
            bp += wv_ * sT[c];
        }
        *(bf16x8*)&wS[((size_t)b*1536 + row)*512 + lane*8] = *(bf16x8*)obuf;
        #pragma unroll
        for (int off = 1; off < 64; off <<= 1) bp += __shfl_xor(bp, off);
        if (lane == 0) beff[b*1536 + row] = bias0 + bp;
    }
}

// ---------------- 128x128 MFMA GEMM v3: DMA staging, BK=64, dbuf --------------
// N widened to 1536: y-blocks 0..7 produce qkT[p][1024] (unchanged path);
// y-blocks 8..11 produce the v panel and TRANSPOSE it in the epilogue through
// the dead lds_a (128x128 bf16 = 32 KB) with a 16B-chunk XOR swizzle
// (chunk ^= c&15: both sides <=2-way bank aliased), storing vv[c][p]
// coalesced along p. Eliminates the separate v-projection dispatch.
__global__ __launch_bounds__(256) void gemm128_kernel(
    const __bf16* __restrict__ A, const __bf16* __restrict__ B,
    const float* __restrict__ bias, int nsplit,
    float scale0, void* __restrict__ out, void* __restrict__ outV,
    int N, int K, long long strideA, long long strideB, long long strideO,
    long long strideV, int biasStride) {
    const int bz = blockIdx.z;
    A += strideA * bz;
    B += strideB * bz;
    const float* bb = bias + (size_t)bz * biasStride;
    const int m0 = blockIdx.x * 128, n0 = blockIdx.y * 128;
    const int tid = threadIdx.x, lane = tid & 63, wave = tid >> 6;
    const int quad = lane >> 4, l16 = lane & 15;
    const int wm = (wave >> 1) * 64, wn = (wave & 1) * 64;

    __shared__ __attribute__((aligned(16))) __bf16 lds_a[2][128][64];
    __shared__ __attribute__((aligned(16))) __bf16 lds_b[2][128][64];

    f32x4 acc[4][4];
    #pragma unroll
    for (int mt = 0; mt < 4; ++mt)
        #pragma unroll
        for (int nt = 0; nt < 4; ++nt)
            #pragma unroll
            for (int r = 0; r < 4; ++r) acc[mt][nt][r] = 0.f;

    const int myrow = (wave << 3) + (lane >> 3);        // 0..31
    const int mych  = ((lane & 7) ^ (myrow & 7)) << 3;  // inverse-swizzled elem chunk
    const __bf16* Ab = A + (size_t)(m0 + myrow) * K + mych;
    const __bf16* Bb = B + (size_t)(n0 + myrow) * K + mych;

    auto stage = [&](int buf, int kt) {
        char* la = (char*)(&lds_a[buf][0][0]) + (wave << 10);
        char* lb = (char*)(&lds_b[buf][0][0]) + (wave << 10);
        #pragma unroll
        for (int i = 0; i < 4; ++i) {
            gload_lds16(Ab + kt + (size_t)(32*i) * K, la + i*4096);
            gload_lds16(Bb + kt + (size_t)(32*i) * K, lb + i*4096);
        }
    };

    stage(0, 0);
    const int NK = K >> 6;
    for (int k8 = 0; k8 < NK; ++k8) {
        __syncthreads();
        const int cur = k8 & 1;
        if (k8 + 1 < NK) stage(cur ^ 1, (k8 + 1) << 6);
        #pragma unroll
        for (int kh = 0; kh < 2; ++kh) {
            bf16x8 af[4], bfr[4];
            #pragma unroll
            for (int mt = 0; mt < 4; ++mt)
                af[mt] = *(const bf16x8*)&lds_a[cur][wm + mt*16 + l16][(((kh<<2)|quad) ^ (l16 & 7)) * 8];
            #pragma unroll
            for (int nt = 0; nt < 4; ++nt)
                bfr[nt] = *(const bf16x8*)&lds_b[cur][wn + nt*16 + l16][(((kh<<2)|quad) ^ (l16 & 7)) * 8];
            #pragma unroll
            for (int mt = 0; mt < 4; ++mt)
                #pragma unroll
                for (int nt = 0; nt < 4; ++nt)
                    acc[mt][nt] = mfma16(af[mt], bfr[nt], acc[mt][nt]);
        }
    }

    if (n0 < 1024) {
        // qk path (unchanged): out[p][1024]
        #pragma unroll
        for (int mt = 0; mt < 4; ++mt) {
            const int mrow = m0 + wm + mt*16 + quad*4;
            #pragma unroll
            for (int nt = 0; nt < 4; ++nt) {
                const int ncol = n0 + wn + nt*16 + l16;
                #pragma unroll
                for (int r = 0; r < 4; ++r) {
                    const int m = mrow + r;
                    float val = acc[mt][nt][r] + bb[ncol];
                    if (ncol < nsplit) val *= scale0;
                    ((__bf16*)out)[(size_t)strideO * bz + (size_t)m * N + ncol] = (__bf16)val;
                }
            }
        }
    } else {
        // v path: transpose through lds_a (uniform branch; barrier is safe)
        __syncthreads();                       // all lds_a reads of the K-loop done
        __bf16* T = (__bf16*)lds_a;            // logical [128][128], chunk-XOR swizzled
        #pragma unroll
        for (int mt = 0; mt < 4; ++mt) {
            const int pl  = wm + mt*16 + quad*4;   // p_local (4 consecutive via r)
            const int pc  = pl >> 3;               // 16B chunk index
            const int hlf = (pl >> 2) & 1;         // low/high half of chunk
            #pragma unroll
            for (int nt = 0; nt < 4; ++nt) {
                const int cl = wn + nt*16 + l16;   // c_local, cl&15 == l16
                const int ncol = n0 + cl;
                __bf16 ob[4];
                #pragma unroll
                for (int r = 0; r < 4; ++r)
                    ob[r] = (__bf16)(acc[mt][nt][r] + bb[ncol]);
                *(bf16x4*)&T[cl*128 + ((pc ^ (cl & 15)) << 3) + hlf*4] = *(bf16x4*)ob;
            }
        }
        __syncthreads();
        const int pch = tid & 15;
        __bf16* vvb = (__bf16*)outV + (size_t)strideV * bz;
        #pragma unroll
        for (int pass = 0; pass < 8; ++pass) {
            const int cl = pass*16 + (tid >> 4);
            bf16x8 vv8 = *(const bf16x8*)&T[cl*128 + ((pch ^ (cl & 15)) << 3)];
            *(bf16x8*)&vvb[(size_t)(n0 - 1024 + cl) * 4096 + m0 + pch*8] = vv8;
        }
    }
}

// ---------------- 64x128 MFMA GEMM v2 (M-tile 64): DMA staging (round 9) -----
template<int OUT_F32, int HAS_RES>
__global__ __launch_bounds__(256) void gemm64_kernel(
    const __bf16* __restrict__ A, const __bf16* __restrict__ B,
    const float* __restrict__ bias, const float* __restrict__ res,
    void* __restrict__ out,
    int N, int K, long long strideA, long long strideB, long long strideO, int biasStride) {
    const int bz = blockIdx.z;
    A += strideA * bz;
    B += strideB * bz;
    const float* bb = bias + (size_t)bz * biasStride;
    const int m0 = blockIdx.x * 64, n0 = blockIdx.y * 128;
    const int tid = threadIdx.x, lane = tid & 63, wave = tid >> 6;
    const int quad = lane >> 4, l16 = lane & 15;
    const int wn = wave * 32;

    __shared__ __attribute__((aligned(16))) __bf16 lds_a[2][64][64];
    __shared__ __attribute__((aligned(16))) __bf16 lds_b[2][128][64];

    f32x4 acc[4][2];
    #pragma unroll
    for (int mt = 0; mt < 4; ++mt)
        #pragma unroll
        for (int nt = 0; nt < 2; ++nt)
            #pragma unroll
            for (int r = 0; r < 4; ++r) acc[mt][nt][r] = 0.f;

    const int myrow = (wave << 3) + (lane >> 3);        // 0..31
    const int mych  = ((lane & 7) ^ (myrow & 7)) << 3;
    const __bf16* Ab = A + (size_t)(m0 + myrow) * K + mych;
    const __bf16* Bb = B + (size_t)(n0 + myrow) * K + mych;

    auto stage = [&](int buf, int kt) {
        char* la = (char*)(&lds_a[buf][0][0]) + (wave << 10);
        char* lb = (char*)(&lds_b[buf][0][0]) + (wave << 10);
        #pragma unroll
        for (int i = 0; i < 2; ++i)
            gload_lds16(Ab + kt + (size_t)(32*i) * K, la + i*4096);
        #pragma unroll
        for (int i = 0; i < 4; ++i)
            gload_lds16(Bb + kt + (size_t)(32*i) * K, lb + i*4096);
    };

    stage(0, 0);
    const int NK = K >> 6;
    for (int k8 = 0; k8 < NK; ++k8) {
        __syncthreads();
        const int cur = k8 & 1;
        if (k8 + 1 < NK) stage(cur ^ 1, (k8 + 1) << 6);
        #pragma unroll
        for (int kh = 0; kh < 2; ++kh) {
            bf16x8 af[4], bfr[2];
            #pragma unroll
            for (int mt = 0; mt < 4; ++mt)
                af[mt] = *(const bf16x8*)&lds_a[cur][mt*16 + l16][(((kh<<2)|quad) ^ (l16 & 7)) * 8];
            #pragma unroll
            for (int nt = 0; nt < 2; ++nt)
                bfr[nt] = *(const bf16x8*)&lds_b[cur][wn + nt*16 + l16][(((kh<<2)|quad) ^ (l16 & 7)) * 8];
            #pragma unroll
            for (int mt = 0; mt < 4; ++mt)
                #pragma unroll
                for (int nt = 0; nt < 2; ++nt)
                    acc[mt][nt] = mfma16(af[mt], bfr[nt], acc[mt][nt]);
        }
    }

    #pragma unroll
    for (int mt = 0; mt < 4; ++mt) {
        const int mrow = m0 + mt*16 + quad*4;
        #pragma unroll
        for (int nt = 0; nt < 2; ++nt) {
            const int ncol = n0 + wn + nt*16 + l16;
            #pragma unroll
            for (int r = 0; r < 4; ++r) {
                const int m = mrow + r;
                float val = acc[mt][nt][r] + bb[m];
                const size_t idx = (size_t)strideO * bz + (size_t)m * N + ncol;
                if constexpr (HAS_RES) val += res[idx];
                if constexpr (OUT_F32) ((float*)out)[idx] = val;
                else ((__bf16*)out)[idx] = (__bf16)val;
            }
        }
    }
}

// ---------------- flash attention v9 (round-7 verified, 78.7 us) ----------------
// Ones-column MFMA row-sums (VALU-lsum variant spills: rounds 2 & 6).
// setprio(1) around compute (verified +1.5us round 7).
// NCH=3 -> grid 16x16x3 = 768 blocks = 3 resident blocks/CU (measured optimum;
// NCH=2's 512 blocks dropped occupancy to 18% and cost +6us -- round 8).
// Iter split 22/21/21 (kt0 = 0/1408/2752).
// qkT: [b][p][1024] bf16 (q pre-scaled by 0.125*log2e); v: [b][c][p] bf16
template<int NCH>
__global__ __launch_bounds__(256, 3) void attn_kernel(const __bf16* __restrict__ qkT,
                                                      const __bf16* __restrict__ v,
                                                      __bf16* __restrict__ attnT,
                                                      __bf16* __restrict__ Opart,
                                                      float* __restrict__ Lpart) {
    const int b = blockIdx.y >> 3, h = blockIdx.y & 7;
    const int chunk = (NCH > 1) ? blockIdx.z : 0;
    int NITER, kt0;
    if constexpr (NCH == 3) {
        NITER = (chunk == 0) ? 22 : 21;
        kt0   = (chunk == 0) ? 0 : (chunk == 1 ? 1408 : 2752);
    } else {
        NITER = 64 / NCH;
        kt0   = chunk * (4096 / NCH);
    }
    const int tid = threadIdx.x;
    const int wave = tid >> 6, lane = tid & 63;
    const int quad = lane >> 4, l16 = lane & 15;
    const int qbase = blockIdx.x * 256 + wave * 64;   // 64 queries per wave

    const __bf16* qkTb = qkT + ((size_t)b << 22);
    const __bf16* vb   = v   + ((size_t)b << 21);

    // double-buffered K/V tiles, XOR-swizzled on 16B chunks: 4x8 KB = 32 KB
    __shared__ __attribute__((aligned(16))) __bf16 lds_k[2][64][64];
    __shared__ __attribute__((aligned(16))) __bf16 lds_v[2][64][64];

    bf16x8 aq[4][2];
    #pragma unroll
    for (int mt = 0; mt < 4; ++mt) {
        const __bf16* qrow = qkTb + (size_t)(qbase + mt*16 + l16) * 1024 + h*64 + quad*8;
        aq[mt][0] = *(const bf16x8*)qrow;
        aq[mt][1] = *(const bf16x8*)(qrow + 32);
    }
    f32x4 o[4][5];   // o[mt][4] accumulates row-sums l via register-ones MFMA
    #pragma unroll
    for (int mt = 0; mt < 4; ++mt)
        #pragma unroll
        for (int dt = 0; dt < 5; ++dt)
            #pragma unroll
            for (int r = 0; r < 4; ++r) o[mt][dt][r] = 0.f;
    const f32x4 kZero = {0.f, 0.f, 0.f, 0.f};

    bf16x8 onesb;
    #pragma unroll
    for (int e = 0; e < 8; ++e) onesb[e] = (__bf16)1.0f;

    // DMA staging geometry: global_load_lds writes linear (wave base + lane*16B).
    // Inverse-swizzle the SOURCE so the linear write realizes col' = col ^ (row&7).
    const int myrow = (wave << 3) + (lane >> 3);
    const int mych  = ((lane & 7) ^ (myrow & 7)) << 3;     // element chunk offset
    const __bf16* kgb = qkTb + (size_t)myrow * 1024 + 512 + h*64 + mych;
    const __bf16* vgb = vb + ((size_t)(h*64 + myrow) << 12) + mych;

    auto stage = [&](int buf, int kt) {
        char* kb = (char*)(&lds_k[buf][0][0]) + (wave << 10);
        char* vp = (char*)(&lds_v[buf][0][0]) + (wave << 10);
        const __bf16* kg = kgb + (size_t)kt * 1024;
        const __bf16* vg = vgb + kt;
        gload_lds16(kg,                       kb);          // K rows 0..31
        gload_lds16(kg + 32*1024,             kb + 4096);   // K rows 32..63
        gload_lds16(vg,                       vp);          // V rows (d) 0..31
        gload_lds16(vg + ((size_t)32 << 12),  vp + 4096);   // V rows (d) 32..63
    };

    stage(0, kt0);   // prologue: tile 0 -> buf 0 (drained by first barrier)

    for (int it = 0; it < NITER; ++it) {
        __syncthreads();           // waits vmcnt(0): tile `it` staged; prior reads done
        const int cur = it & 1;
        if (it + 1 < NITER) stage(cur ^ 1, kt0 + (it + 1) * 64);

        #pragma unroll
        for (int kh = 0; kh < 2; ++kh) {        // key half: keys kh*32 .. kh*32+31
            __builtin_amdgcn_s_setprio(1);
            unsigned pd[4][4];                  // [mt][dword]: nt=2kh(d0,d1), nt=2kh+1(d0,d1)
            #pragma unroll
            for (int j = 0; j < 2; ++j) {
                const int nt = kh*2 + j;
                const int kr = nt*16 + l16;
                bf16x8 bk0 = *(const bf16x8*)&lds_k[cur][kr][( quad      ^ (l16 & 7)) * 8];
                bf16x8 bk1 = *(const bf16x8*)&lds_k[cur][kr][((4 + quad) ^ (l16 & 7)) * 8];
                #pragma unroll
                for (int mt = 0; mt < 4; ++mt) {
                    f32x4 s = mfma16(bk1, aq[mt][1], mfma16(bk0, aq[mt][0], kZero));
                    f32x4 p;
                    #pragma unroll
                    for (int r = 0; r < 4; ++r) p[r] = fast_exp2(s[r]);
                    bf16x4 pb = __builtin_convertvector(p, bf16x4);
                    union { bf16x4 v; unsigned d[2]; } u; u.v = pb;
                    pd[mt][j*2]     = u.d[0];
                    pd[mt][j*2 + 1] = u.d[1];
                }
            }
            // in-register quad redistribution: (X.dw,Y.dw) -> (W_lo, W_hi)
            bf16x8 pa[4];
            #pragma unroll
            for (int mt = 0; mt < 4; ++mt) {
                unsigned x0 = pd[mt][0], x1 = pd[mt][1];
                unsigned y0 = pd[mt][2], y1 = pd[mt][3];
                quad_swap(x0, y0);   // -> W0, W2
                quad_swap(x1, y1);   // -> W1, W3
                union { unsigned d[4]; bf16x8 v; } u;
                u.d[0] = x0; u.d[1] = x1; u.d[2] = y0; u.d[3] = y1;
                pa[mt] = u.v;
            }
            #pragma unroll
            for (int dt = 0; dt < 4; ++dt) {
                bf16x8 bv = *(const bf16x8*)&lds_v[cur][dt*16 + l16][((kh*4 + quad) ^ (l16 & 7)) * 8];
                #pragma unroll
                for (int mt = 0; mt < 4; ++mt)
                    o[mt][dt] = mfma16(pa[mt], bv, o[mt][dt]);
            }
            #pragma unroll
            for (int mt = 0; mt < 4; ++mt)
                o[mt][4] = mfma16(pa[mt], onesb, o[mt][4]);
            __builtin_amdgcn_s_setprio(0);
        }
    }

    if constexpr (NCH > 1) {
        __bf16* Ob = Opart + (size_t)chunk * CHUNK_O;
        #pragma unroll
        for (int mt = 0; mt < 4; ++mt)
            #pragma unroll
            for (int dt = 0; dt < 4; ++dt)
                #pragma unroll
                for (int r = 0; r < 4; ++r) {
                    size_t row = (size_t)b * 4096 + qbase + mt*16 + quad*4 + r;
                    Ob[(row << 9) + (h << 6) + dt*16 + l16] = (__bf16)o[mt][dt][r];
                }
        if (l16 == 0) {
            #pragma unroll
            for (int mt = 0; mt < 4; ++mt)
                #pragma unroll
                for (int r = 0; r < 4; ++r) {
                    int p = qbase + mt*16 + quad*4 + r;
                    Lpart[(size_t)chunk * CHUNK_L + (size_t)(((b*8 + h)) << 12) + p] = o[mt][4][r];
                }
        }
    } else {
        #pragma unroll
        for (int mt = 0; mt < 4; ++mt) {
            float inv[4];
            #pragma unroll
            for (int r = 0; r < 4; ++r)
                inv[r] = 1.f / __shfl(o[mt][4][r], lane & 48);   // broadcast col-0 lane of quad
            #pragma unroll
            for (int dt = 0; dt < 4; ++dt)
                #pragma unroll
                for (int r = 0; r < 4; ++r) {
                    size_t row = (size_t)b * 4096 + qbase + mt*16 + quad*4 + r;
                    attnT[(row << 9) + (h << 6) + dt*16 + l16] = (__bf16)(o[mt][dt][r] * inv[r]);
                }
        }
    }
}

// ---------------- combine split-K partials (bf16) -> attnT bf16 ----------------
// Vectorized: bf16x8 loads/stores (16 B/lane).
template<int NCH>
__global__ __launch_bounds__(256) void attn_combine(const __bf16* __restrict__ Opart,
                                                    const float* __restrict__ Lpart,
                                                    __bf16* __restrict__ attnT) {
    int i = blockIdx.x * 256 + threadIdx.x;   // 524,288 threads, 8 channels each
    int c8 = i & 63;
    int p  = (i >> 6) & 4095;
    int b  = i >> 18;
    int h  = c8 >> 3;
    size_t lidx = (size_t)((b*8 + h) << 12) + p;
    float l = 0.f;
    #pragma unroll
    for (int ch = 0; ch < NCH; ++ch) l += Lpart[(size_t)ch * CHUNK_L + lidx];
    float inv = 1.f / l;
    size_t oi = ((size_t)(b*4096 + p) << 9) + c8*8;   // bf16 elem index
    float acc[8] = {0.f,0.f,0.f,0.f,0.f,0.f,0.f,0.f};
    #pragma unroll
    for (int ch = 0; ch < NCH; ++ch) {
        bf16x8 ov = *(const bf16x8*)&Opart[(size_t)ch * CHUNK_O + oi];
        #pragma unroll
        for (int r = 0; r < 8; ++r) acc[r] += (float)ov[r];
    }
    bf16x8 rv;
    #pragma unroll
    for (int r = 0; r < 8; ++r) rv[r] = (__bf16)(acc[r] * inv);
    *(bf16x8*)&attnT[oi] = rv;
}

extern "C" void kernel_launch(void* const* d_in, const int* in_sizes, int n_in,
                              void* d_out, int out_size, void* d_ws, size_t ws_size,
                              hipStream_t stream) {
    const float* x   = (const float*)d_in[0];
    const float* gnw = (const float*)d_in[1];
    const float* gnb = (const float*)d_in[2];
    const float* wq  = (const float*)d_in[3];
    const float* bq  = (const float*)d_in[4];
    const float* wkv = (const float*)d_in[5];
    const float* bkv = (const float*)d_in[6];
    const float* wo  = (const float*)d_in[7];
    const float* bo  = (const float*)d_in[8];
    float* out = (float*)d_out;

    char* ws = (char*)d_ws;
    float*  stats  = (float*)(ws + OFF_STATS);
    float*  beff   = (float*)(ws + OFF_BEFF);
    __bf16* wS     = (__bf16*)(ws + OFF_W);            // [b][1536][512]
    __bf16* wo_bf  = wS + 2u*1536*512;                 // 512x512
    __bf16* xT     = (__bf16*)(ws + OFF_XNT);          // raw x transposed bf16
    __bf16* qkT    = (__bf16*)(ws + OFF_QKT);
    __bf16* vv     = (__bf16*)(ws + OFF_V);
    __bf16* Opart  = (__bf16*)(ws + OFF_OP);
    __bf16* attnT  = xT;   // xT dead after v-projection; reuse

    // ws requirement for NCH chunks: OFF_OP + NCH*(8 MB Opart + 256 KB Lpart)
    const size_t need3 = (size_t)OFF_OP + 3u * (CHUNK_O * 2 + CHUNK_L * 4);
    const size_t need2 = (size_t)OFF_OP + 2u * (CHUNK_O * 2 + CHUNK_L * 4);
    const int nch = (ws_size >= need3) ? 3 : (ws_size >= need2 ? 2 : 1);
    float* Lpart = (float*)(ws + OFF_OP + (size_t)nch * CHUNK_O * 2);

    hipMemsetAsync(stats, 0, 512, stream);
    // fused GN stats + raw-x transpose/cvt
    gn_fuse<<<dim3(64, 8, 2), 256, 0, stream>>>(x, stats, xT);
    // per-batch scaled weights + effective biases (+ wo cvt)
    prep_w<<<dim3(64, 2), 256, 0, stream>>>(wq, wkv, wo, bq, bkv, stats, gnw, gnb,
                                            wS, wo_bf, beff);

    const long long S  = 2097152LL;   // 4096*512
    const long long S2 = 4194304LL;   // 4096*1024
    const long long SW = 1536LL*512;  // per-batch weight stride
    // merged projection: qkT[p][1024] (y<8) + vv[c][p] via transpose epilogue (y>=8)
    gemm128_kernel<<<dim3(32, 12, 2), 256, 0, stream>>>(
        xT, wS, beff, 512, 0.125f * 1.44269504f, qkT, vv, 1024, 512, S, SW, S2, S, 1536);

    if (nch == 3) {
        attn_kernel<3><<<dim3(16, 16, 3), 256, 0, stream>>>(qkT, vv, nullptr, Opart, Lpart);
        attn_combine<3><<<2048, 256, 0, stream>>>(Opart, Lpart, attnT);
    } else if (nch == 2) {
        attn_kernel<2><<<dim3(16, 16, 2), 256, 0, stream>>>(qkT, vv, nullptr, Opart, Lpart);
        attn_combine<2><<<2048, 256, 0, stream>>>(Opart, Lpart, attnT);
    } else {
        attn_kernel<1><<<dim3(16, 16, 1), 256, 0, stream>>>(qkT, vv, attnT, nullptr, nullptr);
    }

    // out[c][p] = wo * attnOut + bo + residual (fp32)
    gemm64_kernel<1,1><<<dim3(8, 32, 2), 256, 0, stream>>>(
        wo_bf, attnT, bo, x, out, 4096, 512, 0, S, S, 0);
}